// Round 1
// 1039.231 us; speedup vs baseline: 1.1370x; 1.1370x over previous
//
#include <hip/hip_runtime.h>

#define NSTEP 9

typedef __attribute__((ext_vector_type(8)))  __bf16 bf16x8;
typedef __attribute__((ext_vector_type(8)))  short  short8;
typedef __attribute__((ext_vector_type(16))) float  floatx16;

// bf16 round-to-nearest (half-up in magnitude; tie bias negligible)
__device__ __forceinline__ unsigned short bf_hi(float x) {
    unsigned u = __float_as_uint(x);
    return (unsigned short)((u + 0x8000u) >> 16);
}
__device__ __forceinline__ float bf_hi_f(float x) {
    unsigned u = __float_as_uint(x);
    return __uint_as_float((u + 0x8000u) & 0xFFFF0000u);
}
__device__ __forceinline__ unsigned short bf_lo(float x) {
    return bf_hi(x - bf_hi_f(x));
}

__device__ __forceinline__ floatx16 mfma32(bf16x8 a, bf16x8 b, floatx16 c) {
    return __builtin_amdgcn_mfma_f32_32x32x16_bf16(a, b, c, 0, 0, 0);
}
__device__ __forceinline__ bf16x8 cvt(short8 s) {
    return __builtin_bit_cast(bf16x8, s);
}

// ---------------- prep: pack U0/U_rest into 32x32x16 A-fragment layout ------
// ws layout (short8 units): frag f at ws[f*64 + lane]; lane = (hh=lane>>5, m=lane&31)
// A-frag convention (32x32x16): element j of lane -> A[row=m][k=8*hh+j]
//  f=0              : stage-0 frag: A[m][b] = m<16 ? hi(U0[b][m]) : lo(U0[b][m-16])
//  f=1+t*16+2p+var  : step t, a-pair p: A[m][b] = sel(Ur[t][2p+(m>>4)][b][m&15]),
//                     sel = var ? lo : hi.   Rows: m<16 -> a=2p (c=m), m>=16 -> a=2p+1.
__global__ void prep_kernel(const float* __restrict__ U0,
                            const float* __restrict__ Ur,
                            short8* __restrict__ ws)
{
    const int f    = blockIdx.x;     // 0..144
    const int lane = threadIdx.x;    // 0..63
    const int hh = lane >> 5, m = lane & 31;
    short8 v;
    if (f == 0) {
#pragma unroll
        for (int j = 0; j < 8; ++j) {
            int b = 8 * hh + j;
            float u = U0[b * 16 + (m & 15)];
            v[j] = (short)((m < 16) ? bf_hi(u) : bf_lo(u));
        }
    } else {
        int idx = f - 1;               // 0..143
        int var = idx & 1;
        int p   = (idx >> 1) & 7;
        int t   = idx >> 4;
        int a   = 2 * p + (m >> 4);
#pragma unroll
        for (int j = 0; j < 8; ++j) {
            int b = 8 * hh + j;
            float u = Ur[((t * 16 + a) * 16 + b) * 16 + (m & 15)];
            v[j] = (short)(var ? bf_lo(u) : bf_hi(u));
        }
    }
    ws[f * 64 + lane] = v;
}

// ---------------- main ----------------
// Wave = 32 nodes (N-dim of 32x32 MFMA). Per step:
//   V[n,a,c] = sum_b U[a,b,c] h[n,b]        -> MFMA (a-pairs in M rows, 3 hi/lo terms)
//   ris'[n,c] = sum_a ris[n,a] * V[n,a,c]   -> fp32 VALU FMA (ris never leaves fp32)
// Lane (hh,nn): holds ris[c] for c in {4hh..4hh+3, 8+4hh..8+4hh+3} (slots s=0..7),
// matching D rows (reg&3)+8*(reg>>2)+4*hh; regs 0..7 = a-even, 8..15 = a-odd.
__global__ __launch_bounds__(256) void tt_main(
    const float*  __restrict__ ns,    // (n,10,16)
    const short8* __restrict__ Upk,   // packed U frags
    const float*  __restrict__ Uo,    // (16,16)
    float*        __restrict__ out,   // (n,16)
    int n)
{
    const int lane = threadIdx.x & 63;
    const int wv   = threadIdx.x >> 6;
    const int hh   = lane >> 5;       // K-half / row-half
    const int nn   = lane & 31;       // node column within wave
    const int nb   = blockIdx.x * 128 + wv * 32;
    const int n0   = nb + nn;
    const int cn   = (n0 < n) ? n0 : (n - 1);
    const float* g = ns + (size_t)cn * 160 + hh * 8;  // this lane supplies b = 8*hh..8*hh+7

    floatx16 z;
#pragma unroll
    for (int i = 0; i < 16; ++i) z[i] = 0.f;

    float ris[8];
    float4 px0, px1;   // prefetched h for next step

    // ---- stage 0: ris0 = U0^T h0 : rows 0..15 = U0_hi, rows 16..31 = U0_lo ----
    {
        bf16x8 a0 = cvt(Upk[lane]);
        float4 x0 = ((const float4*)g)[0];
        float4 x1 = ((const float4*)g)[1];
        px0 = ((const float4*)(g + 16))[0];           // prefetch plane 1
        px1 = ((const float4*)(g + 16))[1];
        float hv[8] = {x0.x,x0.y,x0.z,x0.w,x1.x,x1.y,x1.z,x1.w};
        short8 bh, bl;
#pragma unroll
        for (int j = 0; j < 8; ++j) { bh[j] = (short)bf_hi(hv[j]); bl[j] = (short)bf_lo(hv[j]); }
        floatx16 D = mfma32(a0, cvt(bh), z);
        D = mfma32(a0, cvt(bl), D);
        // (U0_hi + U0_lo) * (h_hi + h_lo): all four terms present
#pragma unroll
        for (int s = 0; s < 8; ++s) ris[s] = D[s] + D[8 + s];
    }

    // ---- 9 bilinear steps ----
#pragma unroll 1
    for (int t = 0; t < NSTEP; ++t) {
        float hv[8] = {px0.x,px0.y,px0.z,px0.w,px1.x,px1.y,px1.z,px1.w};
        if (t + 1 < NSTEP) {
            px0 = ((const float4*)(g + (t + 2) * 16))[0];
            px1 = ((const float4*)(g + (t + 2) * 16))[1];
        }
        short8 bh, bl;
#pragma unroll
        for (int j = 0; j < 8; ++j) { bh[j] = (short)bf_hi(hv[j]); bl[j] = (short)bf_lo(hv[j]); }
        const bf16x8 vbh = cvt(bh), vbl = cvt(bl);

        // gather ris_a for all a=0..15 of this lane's node (c-slot layout -> shfl)
        float ra[16];
#pragma unroll
        for (int a = 0; a < 16; ++a) {
            const int s   = (a & 3) + 4 * (a >> 3);        // slot holding c=a
            const int src = ((a >> 2) & 1) * 32 + nn;      // lane-half holding c=a
            ra[a] = __shfl(ris[s], src, 64);
        }

        const short8* ub = Upk + 64 + (size_t)t * 1024;    // 16 frags (8 pairs x hi/lo)
        float rn[8];
#pragma unroll
        for (int s = 0; s < 8; ++s) rn[s] = 0.f;
#pragma unroll
        for (int p = 0; p < 8; ++p) {
            bf16x8 uh = cvt(ub[(2 * p + 0) * 64 + lane]);
            bf16x8 ul = cvt(ub[(2 * p + 1) * 64 + lane]);
            // V = U_hi*h_hi + U_hi*h_lo + U_lo*h_hi  (lo*lo ~2^-18, dropped)
            floatx16 D = mfma32(uh, vbh, z);
            D = mfma32(uh, vbl, D);
            D = mfma32(ul, vbh, D);
            const float r0 = ra[2 * p];        // ris[a = 2p]   (rows 0..15 -> regs 0..7)
            const float r1 = ra[2 * p + 1];    // ris[a = 2p+1] (rows 16..31 -> regs 8..15)
#pragma unroll
            for (int s = 0; s < 8; ++s) rn[s] += r0 * D[s] + r1 * D[8 + s];
        }
#pragma unroll
        for (int s = 0; s < 8; ++s) ris[s] = rn[s];
    }

    // ---- output: out[n,cc] = sum_c Uo[c,cc] * ris[c]  (fp32 VALU + pair reduce) ----
    float po[16];
#pragma unroll
    for (int cc = 0; cc < 16; ++cc) po[cc] = 0.f;
#pragma unroll
    for (int s = 0; s < 8; ++s) {
        const int c = 4 * hh + (s & 3) + 8 * (s >> 2);
        const float* urow = Uo + c * 16;
        const float rv = ris[s];
#pragma unroll
        for (int cc = 0; cc < 16; ++cc) po[cc] += urow[cc] * rv;
    }
#pragma unroll
    for (int cc = 0; cc < 16; ++cc) po[cc] += __shfl_xor(po[cc], 32, 64);
    if (n0 < n) {
        const int o = 8 * hh;
        float4 v0, v1;
        v0.x = po[o + 0]; v0.y = po[o + 1]; v0.z = po[o + 2]; v0.w = po[o + 3];
        v1.x = po[o + 4]; v1.y = po[o + 5]; v1.z = po[o + 6]; v1.w = po[o + 7];
        float4* op = (float4*)(out + (size_t)n0 * 16);
        op[2 * hh + 0] = v0;
        op[2 * hh + 1] = v1;
    }
}

extern "C" void kernel_launch(void* const* d_in, const int* in_sizes, int n_in,
                              void* d_out, int out_size, void* d_ws, size_t ws_size,
                              hipStream_t stream) {
    const float* ns = (const float*)d_in[0];
    const float* U0 = (const float*)d_in[1];
    const float* Ur = (const float*)d_in[2];
    const float* Uo = (const float*)d_in[3];
    float* out = (float*)d_out;
    const int n = in_sizes[0] / 160;

    short8* wsv = (short8*)d_ws;
    prep_kernel<<<145, 64, 0, stream>>>(U0, Ur, wsv);

    const int blocks = (n + 127) / 128;
    tt_main<<<blocks, 256, 0, stream>>>(ns, wsv, Uo, out, n);
}